// Round 17
// baseline (12446.869 us; speedup 1.0000x reference)
//
#include <hip/hip_runtime.h>
#include <hip/hip_bf16.h>
#include <stdint.h>

#define T_LEN 1000
#define KIN   69
#define KIN_P 96
#define G3    1536
#define HDIM  512
#define SENT 0xFFFFFFFFu   // bf16 NaN|NaN — unreachable for GRU h in (-1,1)

typedef __attribute__((ext_vector_type(8))) short short8;
typedef __attribute__((ext_vector_type(4))) float f32x4;
typedef __attribute__((ext_vector_type(4))) unsigned int u32x4;

#define MFMA(a,b,c) __builtin_amdgcn_mfma_f32_16x16x32_bf16((a),(b),(c),0,0,0)
#define AGENT __HIP_MEMORY_SCOPE_AGENT

// 16B coherent load (bypass L1+L2, served at LLC) / 8B coherent store / 16B cached load.
#define LDQ(r, p, o) asm volatile("global_load_dwordx4 %0, %1, off offset:" o " sc0 sc1" : "=v"(r) : "v"(p))
#define STQ(p, v)    asm volatile("global_store_dwordx2 %0, %1, off sc0 sc1" :: "v"(p), "v"(v) : "memory")
#define LDC(r, p, o) asm volatile("global_load_dwordx4 %0, %1, off offset:" o : "=v"(r) : "v"(p))

static __device__ __forceinline__ float sigm(float x){ return 1.0f/(1.0f+__expf(-x)); }
static __device__ __forceinline__ float tanh_f(float x){
  float a = fabsf(x);
  float e = __expf(2.0f*a);
  float t = 1.0f - 2.0f/(e+1.0f);
  return x >= 0.0f ? t : -t;
}
static __device__ __forceinline__ unsigned short f2bf(float f){
  union { float f; unsigned int u; } v; v.f = f;
  unsigned int u = v.u;
  return (unsigned short)((u + 0x7fffu + ((u>>16)&1u)) >> 16);   // RNE
}

// ---------------- small converters ----------------
__global__ void k_conv(const float* __restrict__ src, unsigned short* __restrict__ dst, int n){
  int i = blockIdx.x*256 + threadIdx.x;
  if (i < n) dst[i] = f2bf(src[i]);
}
__global__ void k_conv_pad(const float* __restrict__ src, unsigned short* __restrict__ dst,
                           int rows, int ks, int kd){
  int i = blockIdx.x*256 + threadIdx.x;
  int r = i / kd, c = i % kd;
  if (r < rows) dst[i] = (c < ks) ? f2bf(src[r*ks + c]) : (unsigned short)0;
}
__global__ void k_sentinel(float* __restrict__ out, int n){
  int i = blockIdx.x*256 + threadIdx.x;
  if (i < n) out[i] = 1234.5f;
}

// x: [64][69][1000] f32  ->  xT: [(t*64+b)][96] bf16
__global__ void k_xpose(const float* __restrict__ x, unsigned short* __restrict__ xT){
  int b = blockIdx.x & 63, tt = blockIdx.x >> 6;
  int t = tt*64 + threadIdx.x;
  if (t >= T_LEN) return;
  unsigned int* dst = (unsigned int*)(xT + (size_t)(t*64+b)*KIN_P);
  #pragma unroll
  for (int i=0;i<48;i++){
    int k0 = 2*i, k1 = 2*i+1;
    unsigned int lo = (k0<KIN) ? f2bf(x[((size_t)b*KIN + k0)*T_LEN + t]) : 0u;
    unsigned int hi = (k1<KIN) ? f2bf(x[((size_t)b*KIN + k1)*T_LEN + t]) : 0u;
    dst[i] = lo | (hi<<16);
  }
}

// ---------------- layer 0: k-split + A-prefetch pipeline (depth 1) ----------------
// grid 32: dir = bid/16, slice n = bid%16 (j-cols [32n,32n+32)).
// Waves: (m-tile w&3, khalf w>>2). xT A-chunks for step ts+1 issued after the
// recurrent MFMAs, consumed behind vmcnt(12) (3 LDC oldest of 15 in-flight ops;
// publish STQs stay in flight). l0out written as packed dwords on even lanes.
#define NB_B 16
__launch_bounds__(512)
__global__ void k_gru0(const unsigned short* __restrict__ xT,
                       const unsigned short* __restrict__ whh0,
                       const unsigned short* __restrict__ wih0,
                       const float* __restrict__ bih_f, const float* __restrict__ bhh_f,
                       const float* __restrict__ bih_b, const float* __restrict__ bhh_b,
                       unsigned short* __restrict__ l0out,
                       unsigned int* __restrict__ hbuf,   // [2][3][64][256] dwords
                       int pmax)
{
  int bid = blockIdx.x;
  int dir = bid / NB_B;
  int n   = bid % NB_B;
  int j0  = n*32;
  int tid = threadIdx.x;
  int w = tid>>6, l = tid&63;
  int m0    = (w & 3) * 16;
  int khalf = w >> 2;
  int lj = l & 15, lg = l >> 4;

  __shared__ unsigned char lds[96*1024 + 96*192 + 32768];
  unsigned char* whh_lds = lds;
  unsigned char* wih_lds = lds + 96*1024;
  f32x4* part4 = (f32x4*)(lds + 96*1024 + 96*192);
  const unsigned short* whh_g = whh0 + (size_t)dir*G3*HDIM;
  const unsigned short* wih_g = wih0 + (size_t)dir*G3*KIN_P;

  for (int c = tid; c < 96*64; c += 512){
    int lr = c >> 6, c16 = c & 63;
    int g = lr >> 5, jl = lr & 31;
    int gr = g*512 + j0 + jl;
    uint4 v = *(const uint4*)(whh_g + (size_t)gr*HDIM + c16*8);
    *(uint4*)(whh_lds + lr*1024 + ((c16*16) ^ ((lr&7)<<4))) = v;
  }
  for (int c = tid; c < 96*12; c += 512){
    int lr = c / 12, c16 = c % 12;
    int g = lr >> 5, jl = lr & 31;
    int gr = g*512 + j0 + jl;
    uint4 v = *(const uint4*)(wih_g + (size_t)gr*KIN_P + c16*8);
    *(uint4*)(wih_lds + lr*192 + ((c16*16) ^ ((lr&3)<<4))) = v;
  }
  __syncthreads();

  int jg = j0 + khalf*16 + lj;
  const float* bih = dir ? bih_b : bih_f;
  const float* bhh = dir ? bhh_b : bhh_f;
  float brz = bih[jg] + bhh[jg];
  float bzz = bih[512+jg] + bhh[512+jg];
  float bxn = bih[1024+jg];
  float bhn = bhh[1024+jg];
  float hreg[4] = {0.f,0.f,0.f,0.f};
  unsigned int* hb = hbuf + (size_t)dir*3*64*256;
  int wslot = (w&3)*2 + khalf;
  int rslot = (w&3)*2 + (1-khalf);

  // ---- A-prefetch for ts=0 ----
  u32x4 apre0, apre1, apre2;
  {
    int t0 = dir ? (T_LEN-1) : 0;
    const unsigned char* ab = (const unsigned char*)(xT + (size_t)(t0*64 + m0 + lj)*KIN_P + lg*8);
    LDC(apre0, ab, "0"); LDC(apre1, ab, "64"); LDC(apre2, ab, "128");
    asm volatile("s_waitcnt vmcnt(0)" ::: "memory");
    __builtin_amdgcn_sched_barrier(0);
  }

  for (int ts = 0; ts < T_LEN; ts++){
    int t = dir ? (T_LEN-1-ts) : ts;
    int s_r = ts % 3, s_w = (ts+1) % 3, s_s = (ts+2) % 3;

    if (ts > 0){
      // A(ts) LDC are the oldest 3 of ≤15 in-flight ops (then 8 STQ + 4 l0out stores).
      asm volatile("s_waitcnt vmcnt(12)" ::: "memory");
      __builtin_amdgcn_sched_barrier(0);
    }

    // ---- input projection for my j-half (A from registers) ----
    f32x4 xR={0.f,0.f,0.f,0.f}, xZ={0.f,0.f,0.f,0.f}, xXN={0.f,0.f,0.f,0.f};
    #define ISTEP0(qq, kt) { \
      union { u32x4 u; short8 s; } cv; cv.u = qq; \
      int r0 = khalf*16 + lj, r1 = 32 + khalf*16 + lj, r2 = 64 + khalf*16 + lj; \
      int co = (kt)*64 + lg*16; \
      short8 b0 = *(const short8*)(wih_lds + r0*192 + (co ^ ((r0&3)<<4))); \
      short8 b1 = *(const short8*)(wih_lds + r1*192 + (co ^ ((r1&3)<<4))); \
      short8 b2 = *(const short8*)(wih_lds + r2*192 + (co ^ ((r2&3)<<4))); \
      xR  = MFMA(cv.s, b0, xR); \
      xZ  = MFMA(cv.s, b1, xZ); \
      xXN = MFMA(cv.s, b2, xXN); \
    }
    ISTEP0(apre0, 0); ISTEP0(apre1, 1); ISTEP0(apre2, 2);

    // ---- poll + load my k-half of h(ts): 8 x 16B coherent loads ----
    u32x4 q0,q1,q2,q3,q4,q5,q6,q7;
    {
      const unsigned char* hbase = (const unsigned char*)(hb + s_r*64*256)
          + (size_t)(m0+lj)*1024 + (size_t)khalf*512 + lg*16;
      unsigned int ok = 0;
      for (int rounds = 0; ok != 0xFFu && rounds < pmax; ++rounds){
        if(!(ok&0x01)) LDQ(q0, hbase, "0");
        if(!(ok&0x02)) LDQ(q1, hbase, "64");
        if(!(ok&0x04)) LDQ(q2, hbase, "128");
        if(!(ok&0x08)) LDQ(q3, hbase, "192");
        if(!(ok&0x10)) LDQ(q4, hbase, "256");
        if(!(ok&0x20)) LDQ(q5, hbase, "320");
        if(!(ok&0x40)) LDQ(q6, hbase, "384");
        if(!(ok&0x80)) LDQ(q7, hbase, "448");
        asm volatile("s_waitcnt vmcnt(0)" ::: "memory");
        __builtin_amdgcn_sched_barrier(0);
        #define CHK0(qq,bit) if(!(ok&bit) && qq[0]!=SENT && qq[1]!=SENT && qq[2]!=SENT && qq[3]!=SENT) ok|=bit
        CHK0(q0,0x01); CHK0(q1,0x02); CHK0(q2,0x04); CHK0(q3,0x08);
        CHK0(q4,0x10); CHK0(q5,0x20); CHK0(q6,0x40); CHK0(q7,0x80);
      }
    }

    // ---- recurrent partial sums over my k-half, BOTH j-halves ----
    f32x4 pR0={0.f,0.f,0.f,0.f}, pZ0={0.f,0.f,0.f,0.f}, pN0={0.f,0.f,0.f,0.f};
    f32x4 pR1={0.f,0.f,0.f,0.f}, pZ1={0.f,0.f,0.f,0.f}, pN1={0.f,0.f,0.f,0.f};
    #define RSTEP(qq, c) { \
      union { u32x4 u; short8 s; } cv; cv.u = qq; \
      int co = (khalf*8 + (c))*64 + lg*16; \
      { int r = lj;      short8 B = *(const short8*)(whh_lds + r*1024 + (co ^ ((r&7)<<4))); pR0 = MFMA(cv.s, B, pR0); } \
      { int r = 16+lj;   short8 B = *(const short8*)(whh_lds + r*1024 + (co ^ ((r&7)<<4))); pR1 = MFMA(cv.s, B, pR1); } \
      { int r = 32+lj;   short8 B = *(const short8*)(whh_lds + r*1024 + (co ^ ((r&7)<<4))); pZ0 = MFMA(cv.s, B, pZ0); } \
      { int r = 48+lj;   short8 B = *(const short8*)(whh_lds + r*1024 + (co ^ ((r&7)<<4))); pZ1 = MFMA(cv.s, B, pZ1); } \
      { int r = 64+lj;   short8 B = *(const short8*)(whh_lds + r*1024 + (co ^ ((r&7)<<4))); pN0 = MFMA(cv.s, B, pN0); } \
      { int r = 80+lj;   short8 B = *(const short8*)(whh_lds + r*1024 + (co ^ ((r&7)<<4))); pN1 = MFMA(cv.s, B, pN1); } \
    }
    RSTEP(q0,0); RSTEP(q1,1); RSTEP(q2,2); RSTEP(q3,3);
    RSTEP(q4,4); RSTEP(q5,5); RSTEP(q6,6); RSTEP(q7,7);

    // ---- issue A-prefetch for ts+1 (lands during exchange+gates+publish) ----
    {
      int tn = dir ? (t > 0 ? t-1 : 0) : (t < T_LEN-1 ? t+1 : t);
      const unsigned char* ab = (const unsigned char*)(xT + (size_t)(tn*64 + m0 + lj)*KIN_P + lg*8);
      LDC(apre0, ab, "0"); LDC(apre1, ab, "64"); LDC(apre2, ab, "128");
    }

    // ---- exchange: send my other-jh partials, receive my jh from partner ----
    {
      f32x4* wp = part4 + ((size_t)wslot*64 + l)*4;
      if (khalf == 0){ wp[0]=pR1; wp[1]=pZ1; wp[2]=pN1; }
      else           { wp[0]=pR0; wp[1]=pZ0; wp[2]=pN0; }
    }
    __syncthreads();
    f32x4 sR, sZ, sN;
    {
      f32x4* rp = part4 + ((size_t)rslot*64 + l)*4;
      if (khalf == 0){ sR = pR0 + rp[0]; sZ = pZ0 + rp[1]; sN = pN0 + rp[2]; }
      else           { sR = pR1 + rp[0]; sZ = pZ1 + rp[1]; sN = pN1 + rp[2]; }
    }
    __syncthreads();

    // ---- gates ----
    float hnew[4];
    #pragma unroll
    for (int i=0;i<4;i++){
      float r = sigm(xR[i] + sR[i] + brz);
      float z = sigm(xZ[i] + sZ[i] + bzz);
      float nn = tanh_f(xXN[i] + bxn + r*(sN[i] + bhn));
      hnew[i] = (1.0f - z)*nn + z*hreg[i];
      hreg[i] = hnew[i];
    }

    // ---- pack pairs (used by both publish and l0out) ----
    unsigned int packed[4];
    #pragma unroll
    for (int i=0;i<4;i++){
      unsigned short mybf = f2bf(hnew[i]);
      unsigned short ot = (unsigned short)__shfl_xor((int)mybf, 1, 64);
      packed[i] = (unsigned int)mybf | ((unsigned int)ot << 16);
    }

    if (ts < T_LEN-1){
      unsigned long long pk[4];
      #pragma unroll
      for (int i=0;i<4;i++){
        unsigned int nb = (unsigned int)__shfl_down((int)packed[i], 2, 64);
        pk[i] = (unsigned long long)packed[i] | ((unsigned long long)nb << 32);
      }
      if ((l & 3) == 0){
        unsigned long long* hs = (unsigned long long*)(hb + s_s*64*256);
        unsigned long long* hw = (unsigned long long*)(hb + s_w*64*256);
        #pragma unroll
        for (int i=0;i<4;i++){
          int b = m0 + lg*4 + i;
          size_t qi = ((size_t)b*256 + (jg>>1)) >> 1;
          STQ(hs + qi, 0xFFFFFFFFFFFFFFFFull);
          STQ(hw + qi, pk[i]);
        }
      }
    }

    // ---- l0out: packed dword stores on even lanes (same bytes as 2x2B) ----
    if ((l & 1) == 0){
      #pragma unroll
      for (int i=0;i<4;i++){
        int b = m0 + lg*4 + i;
        *(unsigned int*)((unsigned char*)l0out +
            (((size_t)(t*64+b)*1024 + dir*512 + jg) << 1)) = packed[i];
      }
    }
  }
}

// ---------------- layer 1: k-split + A-prefetch pipeline (R16, unchanged) ----------------
__launch_bounds__(512)
__global__ void k_gru1(const unsigned short* __restrict__ l0out,
                       const unsigned short* __restrict__ wih1,
                       const unsigned short* __restrict__ whh1f,
                       const float* __restrict__ bih_f, const float* __restrict__ bhh_f,
                       const float* __restrict__ bih_b, const float* __restrict__ bhh_b,
                       float* __restrict__ l1cat,
                       unsigned int* __restrict__ hbuf,   // [3][64][256] dwords
                       int pmax)
{
  int bid = blockIdx.x;
  int bwd = bid >= 32;
  int n = bwd ? bid - 32 : bid;
  int j0 = n*16;
  int tid = threadIdx.x;
  int w = tid>>6, l = tid&63;
  int mt = w & 3, kh = w >> 2;
  int m0 = mt*16, lj = l&15, lg = l>>4;

  __shared__ unsigned char lds[48*2048 + 48*1024 + 8192];
  unsigned char* wih_lds = lds;
  unsigned char* whh_lds = lds + 48*2048;
  f32x4* partA = (f32x4*)(lds + 48*2048 + 48*1024);          // [4*64] 16B/lane
  f32x4* partB = (f32x4*)(lds + 48*2048 + 48*1024 + 4096);   // [4*64]
  const unsigned short* wih_g = wih1 + (bwd ? (size_t)G3*1024 : 0);

  for (int c = tid; c < 48*128; c += 512){
    int lr = c >> 7, c16 = c & 127;
    int g = lr >> 4, jl = lr & 15;
    int gr = g*512 + j0 + jl;
    uint4 v = *(const uint4*)(wih_g + (size_t)gr*1024 + c16*8);
    *(uint4*)(wih_lds + lr*2048 + ((c16*16) ^ ((lr&7)<<4))) = v;
  }
  if (!bwd){
    for (int c = tid; c < 48*64; c += 512){
      int lr = c >> 6, c16 = c & 63;
      int g = lr >> 4, jl = lr & 15;
      int gr = g*512 + j0 + jl;
      uint4 v = *(const uint4*)(whh1f + (size_t)gr*HDIM + c16*8);
      *(uint4*)(whh_lds + lr*1024 + ((c16*16) ^ ((lr&7)<<4))) = v;
    }
  }
  __syncthreads();

  int jg = j0 + lj;
  const float* bih = bwd ? bih_b : bih_f;
  const float* bhh = bwd ? bhh_b : bhh_f;
  float brz = bih[jg] + bhh[jg];
  float bzz = bih[512+jg] + bhh[512+jg];
  float bxn = bih[1024+jg];
  float bhn = bhh[1024+jg];

  if (bwd){
    int t = T_LEN-1;
    f32x4 xR={0.f,0.f,0.f,0.f}, xZ={0.f,0.f,0.f,0.f}, xN={0.f,0.f,0.f,0.f};
    const unsigned short* arow = l0out + (size_t)(t*64 + m0 + lj)*1024 + lg*8;
    #pragma unroll
    for (int kt=0; kt<16; kt++){
      int ktg = kh*16 + kt;
      short8 a = *(const short8*)(arow + ktg*32);
      int r0 = lj, r1 = 16+lj, r2 = 32+lj;
      int co = ktg*64 + lg*16;
      short8 b0 = *(const short8*)(wih_lds + r0*2048 + (co ^ ((r0&7)<<4)));
      short8 b1 = *(const short8*)(wih_lds + r1*2048 + (co ^ ((r1&7)<<4)));
      short8 b2 = *(const short8*)(wih_lds + r2*2048 + (co ^ ((r2&7)<<4)));
      xR = MFMA(a,b0,xR); xZ = MFMA(a,b1,xZ); xN = MFMA(a,b2,xN);
    }
    int si = mt*64 + l;
    if (kh == 1){ partA[si] = xR; partB[si] = xZ; }
    __syncthreads();
    if (kh == 0){ xR += partA[si]; xZ += partB[si]; }
    __syncthreads();
    if (kh == 1){ partA[si] = xN; }
    __syncthreads();
    if (kh == 0){
      xN += partA[si];
      #pragma unroll
      for (int i=0;i<4;i++){
        float r = sigm(xR[i] + brz);
        float z = sigm(xZ[i] + bzz);
        float nn = tanh_f(xN[i] + bxn + r*bhn);
        l1cat[(size_t)(m0 + lg*4 + i)*1024 + 512 + jg] = (1.0f - z)*nn;
      }
    }
    return;
  }

  float hreg[4] = {0.f,0.f,0.f,0.f};
  int si = mt*64 + l;

  // ---- A-prefetch for ts=0 ----
  u32x4 ap0,ap1,ap2,ap3,ap4,ap5,ap6,ap7,ap8,ap9,ap10,ap11,ap12,ap13,ap14,ap15;
  {
    const unsigned char* ab = (const unsigned char*)(l0out + (size_t)(m0 + lj)*1024 + lg*8)
                              + (size_t)kh*1024;
    LDC(ap0,ab,"0");   LDC(ap1,ab,"64");  LDC(ap2,ab,"128"); LDC(ap3,ab,"192");
    LDC(ap4,ab,"256"); LDC(ap5,ab,"320"); LDC(ap6,ab,"384"); LDC(ap7,ab,"448");
    LDC(ap8,ab,"512"); LDC(ap9,ab,"576"); LDC(ap10,ab,"640");LDC(ap11,ab,"704");
    LDC(ap12,ab,"768");LDC(ap13,ab,"832");LDC(ap14,ab,"896");LDC(ap15,ab,"960");
    asm volatile("s_waitcnt vmcnt(0)" ::: "memory");
    __builtin_amdgcn_sched_barrier(0);
  }

  for (int ts = 0; ts < T_LEN; ts++){
    int s_r = ts % 3, s_w = (ts+1) % 3, s_s = (ts+2) % 3;

    if (ts > 0){
      if (kh == 0) asm volatile("s_waitcnt vmcnt(8)" ::: "memory");
      else         asm volatile("s_waitcnt vmcnt(0)" ::: "memory");
      __builtin_amdgcn_sched_barrier(0);
    }

    // ---- input-proj partial over my K-half (A from registers) ----
    f32x4 xR={0.f,0.f,0.f,0.f}, xZ={0.f,0.f,0.f,0.f}, xN={0.f,0.f,0.f,0.f};
    #define ISTEP(qq, kt) { \
      union { u32x4 u; short8 s; } cv; cv.u = qq; \
      int ktg = kh*16 + (kt); \
      int r0 = lj, r1 = 16+lj, r2 = 32+lj; \
      int co = ktg*64 + lg*16; \
      short8 b0 = *(const short8*)(wih_lds + r0*2048 + (co ^ ((r0&7)<<4))); \
      short8 b1 = *(const short8*)(wih_lds + r1*2048 + (co ^ ((r1&7)<<4))); \
      short8 b2 = *(const short8*)(wih_lds + r2*2048 + (co ^ ((r2&7)<<4))); \
      xR = MFMA(cv.s,b0,xR); xZ = MFMA(cv.s,b1,xZ); xN = MFMA(cv.s,b2,xN); \
    }
    ISTEP(ap0,0);  ISTEP(ap1,1);  ISTEP(ap2,2);  ISTEP(ap3,3);
    ISTEP(ap4,4);  ISTEP(ap5,5);  ISTEP(ap6,6);  ISTEP(ap7,7);
    ISTEP(ap8,8);  ISTEP(ap9,9);  ISTEP(ap10,10); ISTEP(ap11,11);
    ISTEP(ap12,12); ISTEP(ap13,13); ISTEP(ap14,14); ISTEP(ap15,15);

    // ---- poll + load my k-half of h(ts): 8 x 16B coherent loads ----
    u32x4 q0,q1,q2,q3,q4,q5,q6,q7;
    {
      const unsigned char* hbase = (const unsigned char*)(hbuf + s_r*64*256)
          + (size_t)(m0+lj)*1024 + (size_t)kh*512 + lg*16;
      unsigned int ok = 0;
      for (int rounds = 0; ok != 0xFFu && rounds < pmax; ++rounds){
        if(!(ok&0x01)) LDQ(q0, hbase, "0");
        if(!(ok&0x02)) LDQ(q1, hbase, "64");
        if(!(ok&0x04)) LDQ(q2, hbase, "128");
        if(!(ok&0x08)) LDQ(q3, hbase, "192");
        if(!(ok&0x10)) LDQ(q4, hbase, "256");
        if(!(ok&0x20)) LDQ(q5, hbase, "320");
        if(!(ok&0x40)) LDQ(q6, hbase, "384");
        if(!(ok&0x80)) LDQ(q7, hbase, "448");
        asm volatile("s_waitcnt vmcnt(0)" ::: "memory");
        __builtin_amdgcn_sched_barrier(0);
        #define CHK2(qq,bit) if(!(ok&bit) && qq[0]!=SENT && qq[1]!=SENT && qq[2]!=SENT && qq[3]!=SENT) ok|=bit
        CHK2(q0,0x01); CHK2(q1,0x02); CHK2(q2,0x04); CHK2(q3,0x08);
        CHK2(q4,0x10); CHK2(q5,0x20); CHK2(q6,0x40); CHK2(q7,0x80);
      }
    }

    // ---- recurrent partial over my k-half ----
    f32x4 aR={0.f,0.f,0.f,0.f}, aZ={0.f,0.f,0.f,0.f}, aN={0.f,0.f,0.f,0.f};
    #define RSTEP1(qq, c) { \
      union { u32x4 u; short8 s; } cv; cv.u = qq; \
      int co = (kh*8 + (c))*64 + lg*16; \
      { int r = lj;    short8 B = *(const short8*)(whh_lds + r*1024 + (co ^ ((r&7)<<4))); aR = MFMA(cv.s, B, aR); } \
      { int r = 16+lj; short8 B = *(const short8*)(whh_lds + r*1024 + (co ^ ((r&7)<<4))); aZ = MFMA(cv.s, B, aZ); } \
      { int r = 32+lj; short8 B = *(const short8*)(whh_lds + r*1024 + (co ^ ((r&7)<<4))); aN = MFMA(cv.s, B, aN); } \
    }
    RSTEP1(q0,0); RSTEP1(q1,1); RSTEP1(q2,2); RSTEP1(q3,3);
    RSTEP1(q4,4); RSTEP1(q5,5); RSTEP1(q6,6); RSTEP1(q7,7);

    // ---- issue A-prefetch for ts+1 ----
    {
      int tn = (ts+1 < T_LEN) ? ts+1 : ts;
      const unsigned char* ab = (const unsigned char*)(l0out + (size_t)(tn*64 + m0 + lj)*1024 + lg*8)
                                + (size_t)kh*1024;
      LDC(ap0,ab,"0");   LDC(ap1,ab,"64");  LDC(ap2,ab,"128"); LDC(ap3,ab,"192");
      LDC(ap4,ab,"256"); LDC(ap5,ab,"320"); LDC(ap6,ab,"384"); LDC(ap7,ab,"448");
      LDC(ap8,ab,"512"); LDC(ap9,ab,"576"); LDC(ap10,ab,"640");LDC(ap11,ab,"704");
      LDC(ap12,ab,"768");LDC(ap13,ab,"832");LDC(ap14,ab,"896");LDC(ap15,ab,"960");
    }

    // ---- exchange: phase A = merged R,Z; phase B = xN, hN ----
    f32x4 tR = xR + aR, tZ = xZ + aZ;
    if (kh == 1){ partA[si] = tR; partB[si] = tZ; }
    __syncthreads();
    if (kh == 0){ tR += partA[si]; tZ += partB[si]; }
    __syncthreads();
    if (kh == 1){ partA[si] = xN; partB[si] = aN; }
    __syncthreads();
    f32x4 xNt, aNt;
    if (kh == 0){ xNt = xN + partA[si]; aNt = aN + partB[si]; }
    __syncthreads();   // protect buffers before next step's phase-A writes

    if (kh == 0){
      float hnew[4];
      #pragma unroll
      for (int i=0;i<4;i++){
        float r = sigm(tR[i] + brz);
        float z = sigm(tZ[i] + bzz);
        float nn = tanh_f(xNt[i] + bxn + r*(aNt[i] + bhn));
        hnew[i] = (1.0f - z)*nn + z*hreg[i];
        hreg[i] = hnew[i];
      }
      if (ts < T_LEN-1){
        unsigned int packed[4];
        unsigned long long pk[4];
        #pragma unroll
        for (int i=0;i<4;i++){
          unsigned short mybf = f2bf(hnew[i]);
          unsigned short ot = (unsigned short)__shfl_xor((int)mybf, 1, 64);
          packed[i] = (unsigned int)mybf | ((unsigned int)ot << 16);
        }
        #pragma unroll
        for (int i=0;i<4;i++){
          unsigned int nb = (unsigned int)__shfl_down((int)packed[i], 2, 64);
          pk[i] = (unsigned long long)packed[i] | ((unsigned long long)nb << 32);
        }
        if ((l & 3) == 0){
          unsigned long long* hs = (unsigned long long*)(hbuf + s_s*64*256);
          unsigned long long* hw = (unsigned long long*)(hbuf + s_w*64*256);
          #pragma unroll
          for (int i=0;i<4;i++){
            int b = m0 + lg*4 + i;
            size_t qi = ((size_t)b*256 + (jg>>1)) >> 1;
            STQ(hs + qi, 0xFFFFFFFFFFFFFFFFull);
            STQ(hw + qi, pk[i]);
          }
        }
      } else {
        #pragma unroll
        for (int i=0;i<4;i++)
          l1cat[(size_t)(m0 + lg*4 + i)*1024 + jg] = hnew[i];
      }
    }
  }
}

// ---------------- final FC ----------------
__global__ void k_fc(const float* __restrict__ l1cat, const float* __restrict__ fcw,
                     const float* __restrict__ fcb, float* __restrict__ out){
  int idx = blockIdx.x*256 + threadIdx.x;
  if (idx >= 64*12) return;
  int b = idx / 12, o = idx % 12;
  float s = fcb[o];
  for (int k=0;k<1024;k++) s += l1cat[b*1024+k]*fcw[o*1024+k];
  out[idx] = s;
}

extern "C" void kernel_launch(void* const* d_in, const int* in_sizes, int n_in,
                              void* d_out, int out_size, void* d_ws, size_t ws_size,
                              hipStream_t stream){
  const float* x     = (const float*)d_in[0];
  const float* wih0f = (const float*)d_in[1];
  const float* whh0f = (const float*)d_in[2];
  const float* bih0f = (const float*)d_in[3];
  const float* bhh0f = (const float*)d_in[4];
  const float* wih0b = (const float*)d_in[5];
  const float* whh0b = (const float*)d_in[6];
  const float* bih0b = (const float*)d_in[7];
  const float* bhh0b = (const float*)d_in[8];
  const float* wih1f = (const float*)d_in[9];
  const float* whh1f = (const float*)d_in[10];
  const float* bih1f = (const float*)d_in[11];
  const float* bhh1f = (const float*)d_in[12];
  const float* wih1b = (const float*)d_in[13];
  const float* bih1b = (const float*)d_in[15];
  const float* bhh1b = (const float*)d_in[16];
  const float* fcw   = (const float*)d_in[17];
  const float* fcb   = (const float*)d_in[18];

  const size_t SLOT = (size_t)64*256*4;   // 64 KB per ring slot

  char* ws = (char*)d_ws;
  size_t off = 0;
  auto alloc = [&](size_t bytes)->void*{ void* p = ws + off; off = (off + bytes + 255) & ~(size_t)255; return p; };
  unsigned short* xT    = (unsigned short*)alloc((size_t)64000*96*2);
  unsigned short* whh0c = (unsigned short*)alloc((size_t)2*1536*512*2);
  unsigned short* wih0c = (unsigned short*)alloc((size_t)2*1536*96*2);
  unsigned short* wih1c = (unsigned short*)alloc((size_t)2*1536*1024*2);
  unsigned short* whh1c = (unsigned short*)alloc((size_t)1536*512*2);
  unsigned short* l0out = (unsigned short*)alloc((size_t)64000*1024*2);
  unsigned int*   hbB   = (unsigned int*)alloc((size_t)2*3*SLOT);   // [2][3][64][256]
  unsigned int*   hbD   = (unsigned int*)alloc((size_t)3*SLOT);     // [3][64][256]
  float*          l1cat = (float*)alloc((size_t)64*1024*4);

  if (off > ws_size){
    k_sentinel<<<(out_size+255)/256,256,0,stream>>>((float*)d_out, out_size);
    return;
  }

  // ring init: slot 0 = zeros (h0 = 0), slots 1..2 = 0xFF sentinel bytes
  for (int d = 0; d < 2; d++){
    char* base = (char*)hbB + (size_t)d*3*SLOT;
    hipMemsetAsync(base, 0, SLOT, stream);
    hipMemsetAsync(base + SLOT, 0xFF, 2*SLOT, stream);
  }
  hipMemsetAsync(hbD, 0, SLOT, stream);
  hipMemsetAsync((char*)hbD + SLOT, 0xFF, 2*SLOT, stream);

  k_conv<<<3072,256,0,stream>>>(whh0f, whh0c, 786432);
  k_conv<<<3072,256,0,stream>>>(whh0b, whh0c+786432, 786432);
  k_conv_pad<<<576,256,0,stream>>>(wih0f, wih0c, 1536, 69, 96);
  k_conv_pad<<<576,256,0,stream>>>(wih0b, wih0c+1536*96, 1536, 69, 96);
  k_conv<<<6144,256,0,stream>>>(wih1f, wih1c, 1572864);
  k_conv<<<6144,256,0,stream>>>(wih1b, wih1c+1572864, 1572864);
  k_conv<<<3072,256,0,stream>>>(whh1f, whh1c, 786432);
  k_xpose<<<1024,64,0,stream>>>(x, xT);

  k_gru0<<<32,512,0,stream>>>(xT, whh0c, wih0c, bih0f,bhh0f,bih0b,bhh0b, l0out, hbB, 30000);
  k_gru1<<<64,512,0,stream>>>(l0out, wih1c, whh1c, bih1f,bhh1f,bih1b,bhh1b, l1cat, hbD, 30000);
  k_fc<<<3,256,0,stream>>>(l1cat, fcw, fcb, (float*)d_out);
}

// Round 18
// 11818.965 us; speedup vs baseline: 1.0531x; 1.0531x over previous
//
#include <hip/hip_runtime.h>
#include <hip/hip_bf16.h>
#include <stdint.h>

#define T_LEN 1000
#define KIN   69
#define KIN_P 96
#define G3    1536
#define HDIM  512
#define SENT 0xFFFFFFFFu   // bf16 NaN|NaN — unreachable for GRU h in (-1,1)

typedef __attribute__((ext_vector_type(8))) short short8;
typedef __attribute__((ext_vector_type(4))) float f32x4;
typedef __attribute__((ext_vector_type(4))) unsigned int u32x4;

#define MFMA(a,b,c) __builtin_amdgcn_mfma_f32_16x16x32_bf16((a),(b),(c),0,0,0)
#define AGENT __HIP_MEMORY_SCOPE_AGENT

// 16B coherent load (bypass L1+L2, served at LLC) / 8B coherent store / 16B cached load.
#define LDQ(r, p, o) asm volatile("global_load_dwordx4 %0, %1, off offset:" o " sc0 sc1" : "=v"(r) : "v"(p))
#define STQ(p, v)    asm volatile("global_store_dwordx2 %0, %1, off sc0 sc1" :: "v"(p), "v"(v) : "memory")
#define LDC(r, p, o) asm volatile("global_load_dwordx4 %0, %1, off offset:" o : "=v"(r) : "v"(p))

static __device__ __forceinline__ float sigm(float x){ return 1.0f/(1.0f+__expf(-x)); }
static __device__ __forceinline__ float tanh_f(float x){
  float a = fabsf(x);
  float e = __expf(2.0f*a);
  float t = 1.0f - 2.0f/(e+1.0f);
  return x >= 0.0f ? t : -t;
}
static __device__ __forceinline__ unsigned short f2bf(float f){
  union { float f; unsigned int u; } v; v.f = f;
  unsigned int u = v.u;
  return (unsigned short)((u + 0x7fffu + ((u>>16)&1u)) >> 16);   // RNE
}

__global__ void k_sentinel(float* __restrict__ out, int n){
  int i = blockIdx.x*256 + threadIdx.x;
  if (i < n) out[i] = 1234.5f;
}

// ---------------- fused weight conversion: 7 jobs in one launch ----------------
// regions (element offsets): [0,786432) whh0f->whh0c ; [786432,1572864) whh0b->whh0c+786432 ;
// [1572864,1720320) wih0f pad ; [1720320,1867776) wih0b pad ; [1867776,3440640) wih1f ;
// [3440640,5013504) wih1b ; [5013504,5799936) whh1f->whh1c
__global__ void k_convall(const float* __restrict__ whh0f, const float* __restrict__ whh0b,
                          const float* __restrict__ wih0f, const float* __restrict__ wih0b,
                          const float* __restrict__ wih1f, const float* __restrict__ wih1b,
                          const float* __restrict__ whh1f,
                          unsigned short* __restrict__ whh0c, unsigned short* __restrict__ wih0c,
                          unsigned short* __restrict__ wih1c, unsigned short* __restrict__ whh1c){
  int i = blockIdx.x*256 + threadIdx.x;
  if (i >= 5799936) return;
  if (i < 1572864){
    const float* s = (i < 786432) ? whh0f : whh0b;
    int loc = (i < 786432) ? i : i - 786432;
    whh0c[i] = f2bf(s[loc]);
  } else if (i < 1867776){
    int local = i - 1572864;
    int which = local / 147456;
    int rem = local - which*147456;
    int r = rem / KIN_P, c = rem - r*KIN_P;
    const float* s = which ? wih0b : wih0f;
    wih0c[local] = (c < KIN) ? f2bf(s[r*KIN + c]) : (unsigned short)0;
  } else if (i < 5013504){
    int local = i - 1867776;
    const float* s = (local < 1572864) ? wih1f : wih1b;
    int loc = (local < 1572864) ? local : local - 1572864;
    wih1c[local] = f2bf(s[loc]);
  } else {
    int local = i - 5013504;
    whh1c[local] = f2bf(whh1f[local]);
  }
}

// ---------------- fused ring init: hbB (6 slots) + hbD (3 slots), one launch ----------------
// slot pattern: slot index %3 == 0 -> zeros (h0), else SENT bytes.
__global__ void k_ringinit(unsigned int* __restrict__ hbB, unsigned int* __restrict__ hbD){
  int i = blockIdx.x*256 + threadIdx.x;          // over 9*16384 dwords
  if (i >= 9*16384) return;
  int region = i >> 14;                           // 0..8
  int idx = i & 16383;
  if (region < 6){
    hbB[region*16384 + idx] = (region % 3 == 0) ? 0u : SENT;
  } else {
    int r = region - 6;
    hbD[r*16384 + idx] = (r == 0) ? 0u : SENT;
  }
}

// x: [64][69][1000] f32  ->  xT: [(t*64+b)][96] bf16
__global__ void k_xpose(const float* __restrict__ x, unsigned short* __restrict__ xT){
  int b = blockIdx.x & 63, tt = blockIdx.x >> 6;
  int t = tt*64 + threadIdx.x;
  if (t >= T_LEN) return;
  unsigned int* dst = (unsigned int*)(xT + (size_t)(t*64+b)*KIN_P);
  #pragma unroll
  for (int i=0;i<48;i++){
    int k0 = 2*i, k1 = 2*i+1;
    unsigned int lo = (k0<KIN) ? f2bf(x[((size_t)b*KIN + k0)*T_LEN + t]) : 0u;
    unsigned int hi = (k1<KIN) ? f2bf(x[((size_t)b*KIN + k1)*T_LEN + t]) : 0u;
    dst[i] = lo | (hi<<16);
  }
}

// ---------------- layer 0: k-split waves, deduped coherent loads (R14/R16, unchanged) ----------------
#define NB_B 16
__launch_bounds__(512)
__global__ void k_gru0(const unsigned short* __restrict__ xT,
                       const unsigned short* __restrict__ whh0,
                       const unsigned short* __restrict__ wih0,
                       const float* __restrict__ bih_f, const float* __restrict__ bhh_f,
                       const float* __restrict__ bih_b, const float* __restrict__ bhh_b,
                       unsigned short* __restrict__ l0out,
                       unsigned int* __restrict__ hbuf,   // [2][3][64][256] dwords
                       int pmax)
{
  int bid = blockIdx.x;
  int dir = bid / NB_B;
  int n   = bid % NB_B;
  int j0  = n*32;
  int tid = threadIdx.x;
  int w = tid>>6, l = tid&63;
  int m0    = (w & 3) * 16;
  int khalf = w >> 2;
  int lj = l & 15, lg = l >> 4;

  __shared__ unsigned char lds[96*1024 + 96*192 + 32768];
  unsigned char* whh_lds = lds;
  unsigned char* wih_lds = lds + 96*1024;
  f32x4* part4 = (f32x4*)(lds + 96*1024 + 96*192);
  const unsigned short* whh_g = whh0 + (size_t)dir*G3*HDIM;
  const unsigned short* wih_g = wih0 + (size_t)dir*G3*KIN_P;

  for (int c = tid; c < 96*64; c += 512){
    int lr = c >> 6, c16 = c & 63;
    int g = lr >> 5, jl = lr & 31;
    int gr = g*512 + j0 + jl;
    uint4 v = *(const uint4*)(whh_g + (size_t)gr*HDIM + c16*8);
    *(uint4*)(whh_lds + lr*1024 + ((c16*16) ^ ((lr&7)<<4))) = v;
  }
  for (int c = tid; c < 96*12; c += 512){
    int lr = c / 12, c16 = c % 12;
    int g = lr >> 5, jl = lr & 31;
    int gr = g*512 + j0 + jl;
    uint4 v = *(const uint4*)(wih_g + (size_t)gr*KIN_P + c16*8);
    *(uint4*)(wih_lds + lr*192 + ((c16*16) ^ ((lr&3)<<4))) = v;
  }
  __syncthreads();

  int jg = j0 + khalf*16 + lj;
  const float* bih = dir ? bih_b : bih_f;
  const float* bhh = dir ? bhh_b : bhh_f;
  float brz = bih[jg] + bhh[jg];
  float bzz = bih[512+jg] + bhh[512+jg];
  float bxn = bih[1024+jg];
  float bhn = bhh[1024+jg];
  float hreg[4] = {0.f,0.f,0.f,0.f};
  unsigned int* hb = hbuf + (size_t)dir*3*64*256;
  int wslot = (w&3)*2 + khalf;
  int rslot = (w&3)*2 + (1-khalf);

  for (int ts = 0; ts < T_LEN; ts++){
    int t = dir ? (T_LEN-1-ts) : ts;
    int s_r = ts % 3, s_w = (ts+1) % 3, s_s = (ts+2) % 3;

    f32x4 xR={0.f,0.f,0.f,0.f}, xZ={0.f,0.f,0.f,0.f}, xXN={0.f,0.f,0.f,0.f};
    const unsigned short* arow = xT + (size_t)(t*64 + m0 + lj)*KIN_P + lg*8;
    #pragma unroll
    for (int kt=0; kt<3; kt++){
      short8 a = *(const short8*)(arow + kt*32);
      int r0 = khalf*16 + lj, r1 = 32 + khalf*16 + lj, r2 = 64 + khalf*16 + lj;
      int co = kt*64 + lg*16;
      short8 b0 = *(const short8*)(wih_lds + r0*192 + (co ^ ((r0&3)<<4)));
      short8 b1 = *(const short8*)(wih_lds + r1*192 + (co ^ ((r1&3)<<4)));
      short8 b2 = *(const short8*)(wih_lds + r2*192 + (co ^ ((r2&3)<<4)));
      xR  = MFMA(a, b0, xR);
      xZ  = MFMA(a, b1, xZ);
      xXN = MFMA(a, b2, xXN);
    }

    u32x4 q0,q1,q2,q3,q4,q5,q6,q7;
    {
      const unsigned char* hbase = (const unsigned char*)(hb + s_r*64*256)
          + (size_t)(m0+lj)*1024 + (size_t)khalf*512 + lg*16;
      unsigned int ok = 0;
      for (int rounds = 0; ok != 0xFFu && rounds < pmax; ++rounds){
        if(!(ok&0x01)) LDQ(q0, hbase, "0");
        if(!(ok&0x02)) LDQ(q1, hbase, "64");
        if(!(ok&0x04)) LDQ(q2, hbase, "128");
        if(!(ok&0x08)) LDQ(q3, hbase, "192");
        if(!(ok&0x10)) LDQ(q4, hbase, "256");
        if(!(ok&0x20)) LDQ(q5, hbase, "320");
        if(!(ok&0x40)) LDQ(q6, hbase, "384");
        if(!(ok&0x80)) LDQ(q7, hbase, "448");
        asm volatile("s_waitcnt vmcnt(0)" ::: "memory");
        __builtin_amdgcn_sched_barrier(0);
        #define CHK0(qq,bit) if(!(ok&bit) && qq[0]!=SENT && qq[1]!=SENT && qq[2]!=SENT && qq[3]!=SENT) ok|=bit
        CHK0(q0,0x01); CHK0(q1,0x02); CHK0(q2,0x04); CHK0(q3,0x08);
        CHK0(q4,0x10); CHK0(q5,0x20); CHK0(q6,0x40); CHK0(q7,0x80);
      }
    }

    f32x4 pR0={0.f,0.f,0.f,0.f}, pZ0={0.f,0.f,0.f,0.f}, pN0={0.f,0.f,0.f,0.f};
    f32x4 pR1={0.f,0.f,0.f,0.f}, pZ1={0.f,0.f,0.f,0.f}, pN1={0.f,0.f,0.f,0.f};
    #define RSTEP(qq, c) { \
      union { u32x4 u; short8 s; } cv; cv.u = qq; \
      int co = (khalf*8 + (c))*64 + lg*16; \
      { int r = lj;      short8 B = *(const short8*)(whh_lds + r*1024 + (co ^ ((r&7)<<4))); pR0 = MFMA(cv.s, B, pR0); } \
      { int r = 16+lj;   short8 B = *(const short8*)(whh_lds + r*1024 + (co ^ ((r&7)<<4))); pR1 = MFMA(cv.s, B, pR1); } \
      { int r = 32+lj;   short8 B = *(const short8*)(whh_lds + r*1024 + (co ^ ((r&7)<<4))); pZ0 = MFMA(cv.s, B, pZ0); } \
      { int r = 48+lj;   short8 B = *(const short8*)(whh_lds + r*1024 + (co ^ ((r&7)<<4))); pZ1 = MFMA(cv.s, B, pZ1); } \
      { int r = 64+lj;   short8 B = *(const short8*)(whh_lds + r*1024 + (co ^ ((r&7)<<4))); pN0 = MFMA(cv.s, B, pN0); } \
      { int r = 80+lj;   short8 B = *(const short8*)(whh_lds + r*1024 + (co ^ ((r&7)<<4))); pN1 = MFMA(cv.s, B, pN1); } \
    }
    RSTEP(q0,0); RSTEP(q1,1); RSTEP(q2,2); RSTEP(q3,3);
    RSTEP(q4,4); RSTEP(q5,5); RSTEP(q6,6); RSTEP(q7,7);

    {
      f32x4* wp = part4 + ((size_t)wslot*64 + l)*4;
      if (khalf == 0){ wp[0]=pR1; wp[1]=pZ1; wp[2]=pN1; }
      else           { wp[0]=pR0; wp[1]=pZ0; wp[2]=pN0; }
    }
    __syncthreads();
    f32x4 sR, sZ, sN;
    {
      f32x4* rp = part4 + ((size_t)rslot*64 + l)*4;
      if (khalf == 0){ sR = pR0 + rp[0]; sZ = pZ0 + rp[1]; sN = pN0 + rp[2]; }
      else           { sR = pR1 + rp[0]; sZ = pZ1 + rp[1]; sN = pN1 + rp[2]; }
    }
    __syncthreads();

    float hnew[4];
    #pragma unroll
    for (int i=0;i<4;i++){
      float r = sigm(xR[i] + sR[i] + brz);
      float z = sigm(xZ[i] + sZ[i] + bzz);
      float nn = tanh_f(xXN[i] + bxn + r*(sN[i] + bhn));
      hnew[i] = (1.0f - z)*nn + z*hreg[i];
      hreg[i] = hnew[i];
    }

    if (ts < T_LEN-1){
      unsigned int packed[4];
      unsigned long long pk[4];
      #pragma unroll
      for (int i=0;i<4;i++){
        unsigned short mybf = f2bf(hnew[i]);
        unsigned short ot = (unsigned short)__shfl_xor((int)mybf, 1, 64);
        packed[i] = (unsigned int)mybf | ((unsigned int)ot << 16);
      }
      #pragma unroll
      for (int i=0;i<4;i++){
        unsigned int nb = (unsigned int)__shfl_down((int)packed[i], 2, 64);
        pk[i] = (unsigned long long)packed[i] | ((unsigned long long)nb << 32);
      }
      if ((l & 3) == 0){
        unsigned long long* hs = (unsigned long long*)(hb + s_s*64*256);
        unsigned long long* hw = (unsigned long long*)(hb + s_w*64*256);
        #pragma unroll
        for (int i=0;i<4;i++){
          int b = m0 + lg*4 + i;
          size_t qi = ((size_t)b*256 + (jg>>1)) >> 1;
          STQ(hs + qi, 0xFFFFFFFFFFFFFFFFull);
          STQ(hw + qi, pk[i]);
        }
      }
    }

    #pragma unroll
    for (int i=0;i<4;i++){
      int b = m0 + lg*4 + i;
      l0out[(size_t)(t*64+b)*1024 + dir*512 + jg] = f2bf(hnew[i]);
    }
  }
}

// ---------------- layer 1: k-split + A-prefetch pipeline (R16, unchanged) ----------------
__launch_bounds__(512)
__global__ void k_gru1(const unsigned short* __restrict__ l0out,
                       const unsigned short* __restrict__ wih1,
                       const unsigned short* __restrict__ whh1f,
                       const float* __restrict__ bih_f, const float* __restrict__ bhh_f,
                       const float* __restrict__ bih_b, const float* __restrict__ bhh_b,
                       float* __restrict__ l1cat,
                       unsigned int* __restrict__ hbuf,   // [3][64][256] dwords
                       int pmax)
{
  int bid = blockIdx.x;
  int bwd = bid >= 32;
  int n = bwd ? bid - 32 : bid;
  int j0 = n*16;
  int tid = threadIdx.x;
  int w = tid>>6, l = tid&63;
  int mt = w & 3, kh = w >> 2;
  int m0 = mt*16, lj = l&15, lg = l>>4;

  __shared__ unsigned char lds[48*2048 + 48*1024 + 8192];
  unsigned char* wih_lds = lds;
  unsigned char* whh_lds = lds + 48*2048;
  f32x4* partA = (f32x4*)(lds + 48*2048 + 48*1024);          // [4*64] 16B/lane
  f32x4* partB = (f32x4*)(lds + 48*2048 + 48*1024 + 4096);   // [4*64]
  const unsigned short* wih_g = wih1 + (bwd ? (size_t)G3*1024 : 0);

  for (int c = tid; c < 48*128; c += 512){
    int lr = c >> 7, c16 = c & 127;
    int g = lr >> 4, jl = lr & 15;
    int gr = g*512 + j0 + jl;
    uint4 v = *(const uint4*)(wih_g + (size_t)gr*1024 + c16*8);
    *(uint4*)(wih_lds + lr*2048 + ((c16*16) ^ ((lr&7)<<4))) = v;
  }
  if (!bwd){
    for (int c = tid; c < 48*64; c += 512){
      int lr = c >> 6, c16 = c & 63;
      int g = lr >> 4, jl = lr & 15;
      int gr = g*512 + j0 + jl;
      uint4 v = *(const uint4*)(whh1f + (size_t)gr*HDIM + c16*8);
      *(uint4*)(whh_lds + lr*1024 + ((c16*16) ^ ((lr&7)<<4))) = v;
    }
  }
  __syncthreads();

  int jg = j0 + lj;
  const float* bih = bwd ? bih_b : bih_f;
  const float* bhh = bwd ? bhh_b : bhh_f;
  float brz = bih[jg] + bhh[jg];
  float bzz = bih[512+jg] + bhh[512+jg];
  float bxn = bih[1024+jg];
  float bhn = bhh[1024+jg];

  if (bwd){
    int t = T_LEN-1;
    f32x4 xR={0.f,0.f,0.f,0.f}, xZ={0.f,0.f,0.f,0.f}, xN={0.f,0.f,0.f,0.f};
    const unsigned short* arow = l0out + (size_t)(t*64 + m0 + lj)*1024 + lg*8;
    #pragma unroll
    for (int kt=0; kt<16; kt++){
      int ktg = kh*16 + kt;
      short8 a = *(const short8*)(arow + ktg*32);
      int r0 = lj, r1 = 16+lj, r2 = 32+lj;
      int co = ktg*64 + lg*16;
      short8 b0 = *(const short8*)(wih_lds + r0*2048 + (co ^ ((r0&7)<<4)));
      short8 b1 = *(const short8*)(wih_lds + r1*2048 + (co ^ ((r1&7)<<4)));
      short8 b2 = *(const short8*)(wih_lds + r2*2048 + (co ^ ((r2&7)<<4)));
      xR = MFMA(a,b0,xR); xZ = MFMA(a,b1,xZ); xN = MFMA(a,b2,xN);
    }
    int si = mt*64 + l;
    if (kh == 1){ partA[si] = xR; partB[si] = xZ; }
    __syncthreads();
    if (kh == 0){ xR += partA[si]; xZ += partB[si]; }
    __syncthreads();
    if (kh == 1){ partA[si] = xN; }
    __syncthreads();
    if (kh == 0){
      xN += partA[si];
      #pragma unroll
      for (int i=0;i<4;i++){
        float r = sigm(xR[i] + brz);
        float z = sigm(xZ[i] + bzz);
        float nn = tanh_f(xN[i] + bxn + r*bhn);
        l1cat[(size_t)(m0 + lg*4 + i)*1024 + 512 + jg] = (1.0f - z)*nn;
      }
    }
    return;
  }

  float hreg[4] = {0.f,0.f,0.f,0.f};
  int si = mt*64 + l;

  // ---- A-prefetch for ts=0 ----
  u32x4 ap0,ap1,ap2,ap3,ap4,ap5,ap6,ap7,ap8,ap9,ap10,ap11,ap12,ap13,ap14,ap15;
  {
    const unsigned char* ab = (const unsigned char*)(l0out + (size_t)(m0 + lj)*1024 + lg*8)
                              + (size_t)kh*1024;
    LDC(ap0,ab,"0");   LDC(ap1,ab,"64");  LDC(ap2,ab,"128"); LDC(ap3,ab,"192");
    LDC(ap4,ab,"256"); LDC(ap5,ab,"320"); LDC(ap6,ab,"384"); LDC(ap7,ab,"448");
    LDC(ap8,ab,"512"); LDC(ap9,ab,"576"); LDC(ap10,ab,"640");LDC(ap11,ab,"704");
    LDC(ap12,ab,"768");LDC(ap13,ab,"832");LDC(ap14,ab,"896");LDC(ap15,ab,"960");
    asm volatile("s_waitcnt vmcnt(0)" ::: "memory");
    __builtin_amdgcn_sched_barrier(0);
  }

  for (int ts = 0; ts < T_LEN; ts++){
    int s_r = ts % 3, s_w = (ts+1) % 3, s_s = (ts+2) % 3;

    if (ts > 0){
      if (kh == 0) asm volatile("s_waitcnt vmcnt(8)" ::: "memory");
      else         asm volatile("s_waitcnt vmcnt(0)" ::: "memory");
      __builtin_amdgcn_sched_barrier(0);
    }

    // ---- input-proj partial over my K-half (A from registers) ----
    f32x4 xR={0.f,0.f,0.f,0.f}, xZ={0.f,0.f,0.f,0.f}, xN={0.f,0.f,0.f,0.f};
    #define ISTEP(qq, kt) { \
      union { u32x4 u; short8 s; } cv; cv.u = qq; \
      int ktg = kh*16 + (kt); \
      int r0 = lj, r1 = 16+lj, r2 = 32+lj; \
      int co = ktg*64 + lg*16; \
      short8 b0 = *(const short8*)(wih_lds + r0*2048 + (co ^ ((r0&7)<<4))); \
      short8 b1 = *(const short8*)(wih_lds + r1*2048 + (co ^ ((r1&7)<<4))); \
      short8 b2 = *(const short8*)(wih_lds + r2*2048 + (co ^ ((r2&7)<<4))); \
      xR = MFMA(cv.s,b0,xR); xZ = MFMA(cv.s,b1,xZ); xN = MFMA(cv.s,b2,xN); \
    }
    ISTEP(ap0,0);  ISTEP(ap1,1);  ISTEP(ap2,2);  ISTEP(ap3,3);
    ISTEP(ap4,4);  ISTEP(ap5,5);  ISTEP(ap6,6);  ISTEP(ap7,7);
    ISTEP(ap8,8);  ISTEP(ap9,9);  ISTEP(ap10,10); ISTEP(ap11,11);
    ISTEP(ap12,12); ISTEP(ap13,13); ISTEP(ap14,14); ISTEP(ap15,15);

    // ---- poll + load my k-half of h(ts): 8 x 16B coherent loads ----
    u32x4 q0,q1,q2,q3,q4,q5,q6,q7;
    {
      const unsigned char* hbase = (const unsigned char*)(hbuf + s_r*64*256)
          + (size_t)(m0+lj)*1024 + (size_t)kh*512 + lg*16;
      unsigned int ok = 0;
      for (int rounds = 0; ok != 0xFFu && rounds < pmax; ++rounds){
        if(!(ok&0x01)) LDQ(q0, hbase, "0");
        if(!(ok&0x02)) LDQ(q1, hbase, "64");
        if(!(ok&0x04)) LDQ(q2, hbase, "128");
        if(!(ok&0x08)) LDQ(q3, hbase, "192");
        if(!(ok&0x10)) LDQ(q4, hbase, "256");
        if(!(ok&0x20)) LDQ(q5, hbase, "320");
        if(!(ok&0x40)) LDQ(q6, hbase, "384");
        if(!(ok&0x80)) LDQ(q7, hbase, "448");
        asm volatile("s_waitcnt vmcnt(0)" ::: "memory");
        __builtin_amdgcn_sched_barrier(0);
        #define CHK2(qq,bit) if(!(ok&bit) && qq[0]!=SENT && qq[1]!=SENT && qq[2]!=SENT && qq[3]!=SENT) ok|=bit
        CHK2(q0,0x01); CHK2(q1,0x02); CHK2(q2,0x04); CHK2(q3,0x08);
        CHK2(q4,0x10); CHK2(q5,0x20); CHK2(q6,0x40); CHK2(q7,0x80);
      }
    }

    // ---- recurrent partial over my k-half ----
    f32x4 aR={0.f,0.f,0.f,0.f}, aZ={0.f,0.f,0.f,0.f}, aN={0.f,0.f,0.f,0.f};
    #define RSTEP1(qq, c) { \
      union { u32x4 u; short8 s; } cv; cv.u = qq; \
      int co = (kh*8 + (c))*64 + lg*16; \
      { int r = lj;    short8 B = *(const short8*)(whh_lds + r*1024 + (co ^ ((r&7)<<4))); aR = MFMA(cv.s, B, aR); } \
      { int r = 16+lj; short8 B = *(const short8*)(whh_lds + r*1024 + (co ^ ((r&7)<<4))); aZ = MFMA(cv.s, B, aZ); } \
      { int r = 32+lj; short8 B = *(const short8*)(whh_lds + r*1024 + (co ^ ((r&7)<<4))); aN = MFMA(cv.s, B, aN); } \
    }
    RSTEP1(q0,0); RSTEP1(q1,1); RSTEP1(q2,2); RSTEP1(q3,3);
    RSTEP1(q4,4); RSTEP1(q5,5); RSTEP1(q6,6); RSTEP1(q7,7);

    // ---- issue A-prefetch for ts+1 ----
    {
      int tn = (ts+1 < T_LEN) ? ts+1 : ts;
      const unsigned char* ab = (const unsigned char*)(l0out + (size_t)(tn*64 + m0 + lj)*1024 + lg*8)
                                + (size_t)kh*1024;
      LDC(ap0,ab,"0");   LDC(ap1,ab,"64");  LDC(ap2,ab,"128"); LDC(ap3,ab,"192");
      LDC(ap4,ab,"256"); LDC(ap5,ab,"320"); LDC(ap6,ab,"384"); LDC(ap7,ab,"448");
      LDC(ap8,ab,"512"); LDC(ap9,ab,"576"); LDC(ap10,ab,"640");LDC(ap11,ab,"704");
      LDC(ap12,ab,"768");LDC(ap13,ab,"832");LDC(ap14,ab,"896");LDC(ap15,ab,"960");
    }

    // ---- exchange: phase A = merged R,Z; phase B = xN, hN ----
    f32x4 tR = xR + aR, tZ = xZ + aZ;
    if (kh == 1){ partA[si] = tR; partB[si] = tZ; }
    __syncthreads();
    if (kh == 0){ tR += partA[si]; tZ += partB[si]; }
    __syncthreads();
    if (kh == 1){ partA[si] = xN; partB[si] = aN; }
    __syncthreads();
    f32x4 xNt, aNt;
    if (kh == 0){ xNt = xN + partA[si]; aNt = aN + partB[si]; }
    __syncthreads();   // protect buffers before next step's phase-A writes

    if (kh == 0){
      float hnew[4];
      #pragma unroll
      for (int i=0;i<4;i++){
        float r = sigm(tR[i] + brz);
        float z = sigm(tZ[i] + bzz);
        float nn = tanh_f(xNt[i] + bxn + r*(aNt[i] + bhn));
        hnew[i] = (1.0f - z)*nn + z*hreg[i];
        hreg[i] = hnew[i];
      }
      if (ts < T_LEN-1){
        unsigned int packed[4];
        unsigned long long pk[4];
        #pragma unroll
        for (int i=0;i<4;i++){
          unsigned short mybf = f2bf(hnew[i]);
          unsigned short ot = (unsigned short)__shfl_xor((int)mybf, 1, 64);
          packed[i] = (unsigned int)mybf | ((unsigned int)ot << 16);
        }
        #pragma unroll
        for (int i=0;i<4;i++){
          unsigned int nb = (unsigned int)__shfl_down((int)packed[i], 2, 64);
          pk[i] = (unsigned long long)packed[i] | ((unsigned long long)nb << 32);
        }
        if ((l & 3) == 0){
          unsigned long long* hs = (unsigned long long*)(hbuf + s_s*64*256);
          unsigned long long* hw = (unsigned long long*)(hbuf + s_w*64*256);
          #pragma unroll
          for (int i=0;i<4;i++){
            int b = m0 + lg*4 + i;
            size_t qi = ((size_t)b*256 + (jg>>1)) >> 1;
            STQ(hs + qi, 0xFFFFFFFFFFFFFFFFull);
            STQ(hw + qi, pk[i]);
          }
        }
      } else {
        #pragma unroll
        for (int i=0;i<4;i++)
          l1cat[(size_t)(m0 + lg*4 + i)*1024 + jg] = hnew[i];
      }
    }
  }
}

// ---------------- final FC ----------------
__global__ void k_fc(const float* __restrict__ l1cat, const float* __restrict__ fcw,
                     const float* __restrict__ fcb, float* __restrict__ out){
  int idx = blockIdx.x*256 + threadIdx.x;
  if (idx >= 64*12) return;
  int b = idx / 12, o = idx % 12;
  float s = fcb[o];
  for (int k=0;k<1024;k++) s += l1cat[b*1024+k]*fcw[o*1024+k];
  out[idx] = s;
}

extern "C" void kernel_launch(void* const* d_in, const int* in_sizes, int n_in,
                              void* d_out, int out_size, void* d_ws, size_t ws_size,
                              hipStream_t stream){
  const float* x     = (const float*)d_in[0];
  const float* wih0f = (const float*)d_in[1];
  const float* whh0f = (const float*)d_in[2];
  const float* bih0f = (const float*)d_in[3];
  const float* bhh0f = (const float*)d_in[4];
  const float* wih0b = (const float*)d_in[5];
  const float* whh0b = (const float*)d_in[6];
  const float* bih0b = (const float*)d_in[7];
  const float* bhh0b = (const float*)d_in[8];
  const float* wih1f = (const float*)d_in[9];
  const float* whh1f = (const float*)d_in[10];
  const float* bih1f = (const float*)d_in[11];
  const float* bhh1f = (const float*)d_in[12];
  const float* wih1b = (const float*)d_in[13];
  const float* bih1b = (const float*)d_in[15];
  const float* bhh1b = (const float*)d_in[16];
  const float* fcw   = (const float*)d_in[17];
  const float* fcb   = (const float*)d_in[18];

  const size_t SLOT = (size_t)64*256*4;   // 64 KB per ring slot

  char* ws = (char*)d_ws;
  size_t off = 0;
  auto alloc = [&](size_t bytes)->void*{ void* p = ws + off; off = (off + bytes + 255) & ~(size_t)255; return p; };
  unsigned short* xT    = (unsigned short*)alloc((size_t)64000*96*2);
  unsigned short* whh0c = (unsigned short*)alloc((size_t)2*1536*512*2);
  unsigned short* wih0c = (unsigned short*)alloc((size_t)2*1536*96*2);
  unsigned short* wih1c = (unsigned short*)alloc((size_t)2*1536*1024*2);
  unsigned short* whh1c = (unsigned short*)alloc((size_t)1536*512*2);
  unsigned short* l0out = (unsigned short*)alloc((size_t)64000*1024*2);
  unsigned int*   hbB   = (unsigned int*)alloc((size_t)2*3*SLOT);   // [2][3][64][256]
  unsigned int*   hbD   = (unsigned int*)alloc((size_t)3*SLOT);     // [3][64][256]
  float*          l1cat = (float*)alloc((size_t)64*1024*4);

  if (off > ws_size){
    k_sentinel<<<(out_size+255)/256,256,0,stream>>>((float*)d_out, out_size);
    return;
  }

  // fused conversions + ring init (2 launches instead of 12)
  k_convall<<<22656,256,0,stream>>>(whh0f, whh0b, wih0f, wih0b, wih1f, wih1b, whh1f,
                                    whh0c, wih0c, wih1c, whh1c);
  k_ringinit<<<576,256,0,stream>>>(hbB, hbD);
  k_xpose<<<1024,64,0,stream>>>(x, xT);

  k_gru0<<<32,512,0,stream>>>(xT, whh0c, wih0c, bih0f,bhh0f,bih0b,bhh0b, l0out, hbB, 30000);
  k_gru1<<<64,512,0,stream>>>(l0out, wih1c, whh1c, bih1f,bhh1f,bih1b,bhh1b, l1cat, hbD, 30000);
  k_fc<<<3,256,0,stream>>>(l1cat, fcw, fcb, (float*)d_out);
}

// Round 19
// 11740.263 us; speedup vs baseline: 1.0602x; 1.0067x over previous
//
#include <hip/hip_runtime.h>
#include <hip/hip_bf16.h>
#include <stdint.h>

#define T_LEN 1000
#define KIN   69
#define KIN_P 96
#define G3    1536
#define HDIM  512
#define SENT 0xFFFFFFFFu   // bf16 NaN|NaN — unreachable for GRU h in (-1,1)

typedef __attribute__((ext_vector_type(8))) short short8;
typedef __attribute__((ext_vector_type(4))) float f32x4;
typedef __attribute__((ext_vector_type(4))) unsigned int u32x4;

#define MFMA(a,b,c) __builtin_amdgcn_mfma_f32_16x16x32_bf16((a),(b),(c),0,0,0)
#define AGENT __HIP_MEMORY_SCOPE_AGENT

// 16B coherent load (bypass L1+L2, served at LLC) / 8B coherent store / 16B cached load.
#define LDQ(r, p, o) asm volatile("global_load_dwordx4 %0, %1, off offset:" o " sc0 sc1" : "=v"(r) : "v"(p))
#define STQ(p, v)    asm volatile("global_store_dwordx2 %0, %1, off sc0 sc1" :: "v"(p), "v"(v) : "memory")
#define LDC(r, p, o) asm volatile("global_load_dwordx4 %0, %1, off offset:" o : "=v"(r) : "v"(p))

static __device__ __forceinline__ float sigm(float x){ return 1.0f/(1.0f+__expf(-x)); }
static __device__ __forceinline__ float tanh_f(float x){
  float a = fabsf(x);
  float e = __expf(2.0f*a);
  float t = 1.0f - 2.0f/(e+1.0f);
  return x >= 0.0f ? t : -t;
}
static __device__ __forceinline__ unsigned short f2bf(float f){
  union { float f; unsigned int u; } v; v.f = f;
  unsigned int u = v.u;
  return (unsigned short)((u + 0x7fffu + ((u>>16)&1u)) >> 16);   // RNE
}

__global__ void k_sentinel(float* __restrict__ out, int n){
  int i = blockIdx.x*256 + threadIdx.x;
  if (i < n) out[i] = 1234.5f;
}

// ---------------- fused weight conversion: 7 jobs in one launch ----------------
__global__ void k_convall(const float* __restrict__ whh0f, const float* __restrict__ whh0b,
                          const float* __restrict__ wih0f, const float* __restrict__ wih0b,
                          const float* __restrict__ wih1f, const float* __restrict__ wih1b,
                          const float* __restrict__ whh1f,
                          unsigned short* __restrict__ whh0c, unsigned short* __restrict__ wih0c,
                          unsigned short* __restrict__ wih1c, unsigned short* __restrict__ whh1c){
  int i = blockIdx.x*256 + threadIdx.x;
  if (i >= 5799936) return;
  if (i < 1572864){
    const float* s = (i < 786432) ? whh0f : whh0b;
    int loc = (i < 786432) ? i : i - 786432;
    whh0c[i] = f2bf(s[loc]);
  } else if (i < 1867776){
    int local = i - 1572864;
    int which = local / 147456;
    int rem = local - which*147456;
    int r = rem / KIN_P, c = rem - r*KIN_P;
    const float* s = which ? wih0b : wih0f;
    wih0c[local] = (c < KIN) ? f2bf(s[r*KIN + c]) : (unsigned short)0;
  } else if (i < 5013504){
    int local = i - 1867776;
    const float* s = (local < 1572864) ? wih1f : wih1b;
    int loc = (local < 1572864) ? local : local - 1572864;
    wih1c[local] = f2bf(s[loc]);
  } else {
    int local = i - 5013504;
    whh1c[local] = f2bf(whh1f[local]);
  }
}

// ---------------- fused ring init ----------------
__global__ void k_ringinit(unsigned int* __restrict__ hbB, unsigned int* __restrict__ hbD){
  int i = blockIdx.x*256 + threadIdx.x;
  if (i >= 9*16384) return;
  int region = i >> 14;
  int idx = i & 16383;
  if (region < 6){
    hbB[region*16384 + idx] = (region % 3 == 0) ? 0u : SENT;
  } else {
    int r = region - 6;
    hbD[r*16384 + idx] = (r == 0) ? 0u : SENT;
  }
}

// x: [64][69][1000] f32  ->  xT: [(t*64+b)][96] bf16
__global__ void k_xpose(const float* __restrict__ x, unsigned short* __restrict__ xT){
  int b = blockIdx.x & 63, tt = blockIdx.x >> 6;
  int t = tt*64 + threadIdx.x;
  if (t >= T_LEN) return;
  unsigned int* dst = (unsigned int*)(xT + (size_t)(t*64+b)*KIN_P);
  #pragma unroll
  for (int i=0;i<48;i++){
    int k0 = 2*i, k1 = 2*i+1;
    unsigned int lo = (k0<KIN) ? f2bf(x[((size_t)b*KIN + k0)*T_LEN + t]) : 0u;
    unsigned int hi = (k1<KIN) ? f2bf(x[((size_t)b*KIN + k1)*T_LEN + t]) : 0u;
    dst[i] = lo | (hi<<16);
  }
}

// ---------------- layer 0: k-split waves, deduped coherent loads (R14/R18, unchanged) ----------------
#define NB_B 16
__launch_bounds__(512)
__global__ void k_gru0(const unsigned short* __restrict__ xT,
                       const unsigned short* __restrict__ whh0,
                       const unsigned short* __restrict__ wih0,
                       const float* __restrict__ bih_f, const float* __restrict__ bhh_f,
                       const float* __restrict__ bih_b, const float* __restrict__ bhh_b,
                       unsigned short* __restrict__ l0out,
                       unsigned int* __restrict__ hbuf,   // [2][3][64][256] dwords
                       int pmax)
{
  int bid = blockIdx.x;
  int dir = bid / NB_B;
  int n   = bid % NB_B;
  int j0  = n*32;
  int tid = threadIdx.x;
  int w = tid>>6, l = tid&63;
  int m0    = (w & 3) * 16;
  int khalf = w >> 2;
  int lj = l & 15, lg = l >> 4;

  __shared__ unsigned char lds[96*1024 + 96*192 + 32768];
  unsigned char* whh_lds = lds;
  unsigned char* wih_lds = lds + 96*1024;
  f32x4* part4 = (f32x4*)(lds + 96*1024 + 96*192);
  const unsigned short* whh_g = whh0 + (size_t)dir*G3*HDIM;
  const unsigned short* wih_g = wih0 + (size_t)dir*G3*KIN_P;

  for (int c = tid; c < 96*64; c += 512){
    int lr = c >> 6, c16 = c & 63;
    int g = lr >> 5, jl = lr & 31;
    int gr = g*512 + j0 + jl;
    uint4 v = *(const uint4*)(whh_g + (size_t)gr*HDIM + c16*8);
    *(uint4*)(whh_lds + lr*1024 + ((c16*16) ^ ((lr&7)<<4))) = v;
  }
  for (int c = tid; c < 96*12; c += 512){
    int lr = c / 12, c16 = c % 12;
    int g = lr >> 5, jl = lr & 31;
    int gr = g*512 + j0 + jl;
    uint4 v = *(const uint4*)(wih_g + (size_t)gr*KIN_P + c16*8);
    *(uint4*)(wih_lds + lr*192 + ((c16*16) ^ ((lr&3)<<4))) = v;
  }
  __syncthreads();

  int jg = j0 + khalf*16 + lj;
  const float* bih = dir ? bih_b : bih_f;
  const float* bhh = dir ? bhh_b : bhh_f;
  float brz = bih[jg] + bhh[jg];
  float bzz = bih[512+jg] + bhh[512+jg];
  float bxn = bih[1024+jg];
  float bhn = bhh[1024+jg];
  float hreg[4] = {0.f,0.f,0.f,0.f};
  unsigned int* hb = hbuf + (size_t)dir*3*64*256;
  int wslot = (w&3)*2 + khalf;
  int rslot = (w&3)*2 + (1-khalf);

  for (int ts = 0; ts < T_LEN; ts++){
    int t = dir ? (T_LEN-1-ts) : ts;
    int s_r = ts % 3, s_w = (ts+1) % 3, s_s = (ts+2) % 3;

    f32x4 xR={0.f,0.f,0.f,0.f}, xZ={0.f,0.f,0.f,0.f}, xXN={0.f,0.f,0.f,0.f};
    const unsigned short* arow = xT + (size_t)(t*64 + m0 + lj)*KIN_P + lg*8;
    #pragma unroll
    for (int kt=0; kt<3; kt++){
      short8 a = *(const short8*)(arow + kt*32);
      int r0 = khalf*16 + lj, r1 = 32 + khalf*16 + lj, r2 = 64 + khalf*16 + lj;
      int co = kt*64 + lg*16;
      short8 b0 = *(const short8*)(wih_lds + r0*192 + (co ^ ((r0&3)<<4)));
      short8 b1 = *(const short8*)(wih_lds + r1*192 + (co ^ ((r1&3)<<4)));
      short8 b2 = *(const short8*)(wih_lds + r2*192 + (co ^ ((r2&3)<<4)));
      xR  = MFMA(a, b0, xR);
      xZ  = MFMA(a, b1, xZ);
      xXN = MFMA(a, b2, xXN);
    }

    u32x4 q0,q1,q2,q3,q4,q5,q6,q7;
    {
      const unsigned char* hbase = (const unsigned char*)(hb + s_r*64*256)
          + (size_t)(m0+lj)*1024 + (size_t)khalf*512 + lg*16;
      unsigned int ok = 0;
      for (int rounds = 0; ok != 0xFFu && rounds < pmax; ++rounds){
        if(!(ok&0x01)) LDQ(q0, hbase, "0");
        if(!(ok&0x02)) LDQ(q1, hbase, "64");
        if(!(ok&0x04)) LDQ(q2, hbase, "128");
        if(!(ok&0x08)) LDQ(q3, hbase, "192");
        if(!(ok&0x10)) LDQ(q4, hbase, "256");
        if(!(ok&0x20)) LDQ(q5, hbase, "320");
        if(!(ok&0x40)) LDQ(q6, hbase, "384");
        if(!(ok&0x80)) LDQ(q7, hbase, "448");
        asm volatile("s_waitcnt vmcnt(0)" ::: "memory");
        __builtin_amdgcn_sched_barrier(0);
        #define CHK0(qq,bit) if(!(ok&bit) && qq[0]!=SENT && qq[1]!=SENT && qq[2]!=SENT && qq[3]!=SENT) ok|=bit
        CHK0(q0,0x01); CHK0(q1,0x02); CHK0(q2,0x04); CHK0(q3,0x08);
        CHK0(q4,0x10); CHK0(q5,0x20); CHK0(q6,0x40); CHK0(q7,0x80);
      }
    }

    f32x4 pR0={0.f,0.f,0.f,0.f}, pZ0={0.f,0.f,0.f,0.f}, pN0={0.f,0.f,0.f,0.f};
    f32x4 pR1={0.f,0.f,0.f,0.f}, pZ1={0.f,0.f,0.f,0.f}, pN1={0.f,0.f,0.f,0.f};
    #define RSTEP(qq, c) { \
      union { u32x4 u; short8 s; } cv; cv.u = qq; \
      int co = (khalf*8 + (c))*64 + lg*16; \
      { int r = lj;      short8 B = *(const short8*)(whh_lds + r*1024 + (co ^ ((r&7)<<4))); pR0 = MFMA(cv.s, B, pR0); } \
      { int r = 16+lj;   short8 B = *(const short8*)(whh_lds + r*1024 + (co ^ ((r&7)<<4))); pR1 = MFMA(cv.s, B, pR1); } \
      { int r = 32+lj;   short8 B = *(const short8*)(whh_lds + r*1024 + (co ^ ((r&7)<<4))); pZ0 = MFMA(cv.s, B, pZ0); } \
      { int r = 48+lj;   short8 B = *(const short8*)(whh_lds + r*1024 + (co ^ ((r&7)<<4))); pZ1 = MFMA(cv.s, B, pZ1); } \
      { int r = 64+lj;   short8 B = *(const short8*)(whh_lds + r*1024 + (co ^ ((r&7)<<4))); pN0 = MFMA(cv.s, B, pN0); } \
      { int r = 80+lj;   short8 B = *(const short8*)(whh_lds + r*1024 + (co ^ ((r&7)<<4))); pN1 = MFMA(cv.s, B, pN1); } \
    }
    RSTEP(q0,0); RSTEP(q1,1); RSTEP(q2,2); RSTEP(q3,3);
    RSTEP(q4,4); RSTEP(q5,5); RSTEP(q6,6); RSTEP(q7,7);

    {
      f32x4* wp = part4 + ((size_t)wslot*64 + l)*4;
      if (khalf == 0){ wp[0]=pR1; wp[1]=pZ1; wp[2]=pN1; }
      else           { wp[0]=pR0; wp[1]=pZ0; wp[2]=pN0; }
    }
    __syncthreads();
    f32x4 sR, sZ, sN;
    {
      f32x4* rp = part4 + ((size_t)rslot*64 + l)*4;
      if (khalf == 0){ sR = pR0 + rp[0]; sZ = pZ0 + rp[1]; sN = pN0 + rp[2]; }
      else           { sR = pR1 + rp[0]; sZ = pZ1 + rp[1]; sN = pN1 + rp[2]; }
    }
    __syncthreads();

    float hnew[4];
    #pragma unroll
    for (int i=0;i<4;i++){
      float r = sigm(xR[i] + sR[i] + brz);
      float z = sigm(xZ[i] + sZ[i] + bzz);
      float nn = tanh_f(xXN[i] + bxn + r*(sN[i] + bhn));
      hnew[i] = (1.0f - z)*nn + z*hreg[i];
      hreg[i] = hnew[i];
    }

    if (ts < T_LEN-1){
      unsigned int packed[4];
      unsigned long long pk[4];
      #pragma unroll
      for (int i=0;i<4;i++){
        unsigned short mybf = f2bf(hnew[i]);
        unsigned short ot = (unsigned short)__shfl_xor((int)mybf, 1, 64);
        packed[i] = (unsigned int)mybf | ((unsigned int)ot << 16);
      }
      #pragma unroll
      for (int i=0;i<4;i++){
        unsigned int nb = (unsigned int)__shfl_down((int)packed[i], 2, 64);
        pk[i] = (unsigned long long)packed[i] | ((unsigned long long)nb << 32);
      }
      if ((l & 3) == 0){
        unsigned long long* hs = (unsigned long long*)(hb + s_s*64*256);
        unsigned long long* hw = (unsigned long long*)(hb + s_w*64*256);
        #pragma unroll
        for (int i=0;i<4;i++){
          int b = m0 + lg*4 + i;
          size_t qi = ((size_t)b*256 + (jg>>1)) >> 1;
          STQ(hs + qi, 0xFFFFFFFFFFFFFFFFull);
          STQ(hw + qi, pk[i]);
        }
      }
    }

    #pragma unroll
    for (int i=0;i<4;i++){
      int b = m0 + lg*4 + i;
      l0out[(size_t)(t*64+b)*1024 + dir*512 + jg] = f2bf(hnew[i]);
    }
  }
}

// ---------------- layer 1: k-split + A-prefetch + SINGLE-PHASE exchange ----------------
// Exchange: kh=1 writes tR,tZ,xN,aN into 4 x 4KB LDS buffers; 1 barrier; kh=0 reads
// and finalizes; 1 protect barrier. LDS total = 163840 B (the 160 KiB hw max).
__launch_bounds__(512)
__global__ void k_gru1(const unsigned short* __restrict__ l0out,
                       const unsigned short* __restrict__ wih1,
                       const unsigned short* __restrict__ whh1f,
                       const float* __restrict__ bih_f, const float* __restrict__ bhh_f,
                       const float* __restrict__ bih_b, const float* __restrict__ bhh_b,
                       float* __restrict__ l1cat,
                       unsigned int* __restrict__ hbuf,   // [3][64][256] dwords
                       int pmax)
{
  int bid = blockIdx.x;
  int bwd = bid >= 32;
  int n = bwd ? bid - 32 : bid;
  int j0 = n*16;
  int tid = threadIdx.x;
  int w = tid>>6, l = tid&63;
  int mt = w & 3, kh = w >> 2;
  int m0 = mt*16, lj = l&15, lg = l>>4;

  __shared__ unsigned char lds[48*2048 + 48*1024 + 16384];   // = 163840 B
  unsigned char* wih_lds = lds;
  unsigned char* whh_lds = lds + 48*2048;
  f32x4* partA = (f32x4*)(lds + 48*2048 + 48*1024);          // [256] 16B/lane
  f32x4* partB = partA + 256;
  f32x4* partC = partA + 512;
  f32x4* partD = partA + 768;
  const unsigned short* wih_g = wih1 + (bwd ? (size_t)G3*1024 : 0);

  for (int c = tid; c < 48*128; c += 512){
    int lr = c >> 7, c16 = c & 127;
    int g = lr >> 4, jl = lr & 15;
    int gr = g*512 + j0 + jl;
    uint4 v = *(const uint4*)(wih_g + (size_t)gr*1024 + c16*8);
    *(uint4*)(wih_lds + lr*2048 + ((c16*16) ^ ((lr&7)<<4))) = v;
  }
  if (!bwd){
    for (int c = tid; c < 48*64; c += 512){
      int lr = c >> 6, c16 = c & 63;
      int g = lr >> 4, jl = lr & 15;
      int gr = g*512 + j0 + jl;
      uint4 v = *(const uint4*)(whh1f + (size_t)gr*HDIM + c16*8);
      *(uint4*)(whh_lds + lr*1024 + ((c16*16) ^ ((lr&7)<<4))) = v;
    }
  }
  __syncthreads();

  int jg = j0 + lj;
  const float* bih = bwd ? bih_b : bih_f;
  const float* bhh = bwd ? bhh_b : bhh_f;
  float brz = bih[jg] + bhh[jg];
  float bzz = bih[512+jg] + bhh[512+jg];
  float bxn = bih[1024+jg];
  float bhn = bhh[1024+jg];

  if (bwd){
    int t = T_LEN-1;
    f32x4 xR={0.f,0.f,0.f,0.f}, xZ={0.f,0.f,0.f,0.f}, xN={0.f,0.f,0.f,0.f};
    const unsigned short* arow = l0out + (size_t)(t*64 + m0 + lj)*1024 + lg*8;
    #pragma unroll
    for (int kt=0; kt<16; kt++){
      int ktg = kh*16 + kt;
      short8 a = *(const short8*)(arow + ktg*32);
      int r0 = lj, r1 = 16+lj, r2 = 32+lj;
      int co = ktg*64 + lg*16;
      short8 b0 = *(const short8*)(wih_lds + r0*2048 + (co ^ ((r0&7)<<4)));
      short8 b1 = *(const short8*)(wih_lds + r1*2048 + (co ^ ((r1&7)<<4)));
      short8 b2 = *(const short8*)(wih_lds + r2*2048 + (co ^ ((r2&7)<<4)));
      xR = MFMA(a,b0,xR); xZ = MFMA(a,b1,xZ); xN = MFMA(a,b2,xN);
    }
    int si = mt*64 + l;
    if (kh == 1){ partA[si] = xR; partB[si] = xZ; partC[si] = xN; }
    __syncthreads();
    if (kh == 0){
      xR += partA[si]; xZ += partB[si]; xN += partC[si];
      #pragma unroll
      for (int i=0;i<4;i++){
        float r = sigm(xR[i] + brz);
        float z = sigm(xZ[i] + bzz);
        float nn = tanh_f(xN[i] + bxn + r*bhn);
        l1cat[(size_t)(m0 + lg*4 + i)*1024 + 512 + jg] = (1.0f - z)*nn;
      }
    }
    return;
  }

  float hreg[4] = {0.f,0.f,0.f,0.f};
  int si = mt*64 + l;

  // ---- A-prefetch for ts=0 ----
  u32x4 ap0,ap1,ap2,ap3,ap4,ap5,ap6,ap7,ap8,ap9,ap10,ap11,ap12,ap13,ap14,ap15;
  {
    const unsigned char* ab = (const unsigned char*)(l0out + (size_t)(m0 + lj)*1024 + lg*8)
                              + (size_t)kh*1024;
    LDC(ap0,ab,"0");   LDC(ap1,ab,"64");  LDC(ap2,ab,"128"); LDC(ap3,ab,"192");
    LDC(ap4,ab,"256"); LDC(ap5,ab,"320"); LDC(ap6,ab,"384"); LDC(ap7,ab,"448");
    LDC(ap8,ab,"512"); LDC(ap9,ab,"576"); LDC(ap10,ab,"640");LDC(ap11,ab,"704");
    LDC(ap12,ab,"768");LDC(ap13,ab,"832");LDC(ap14,ab,"896");LDC(ap15,ab,"960");
    asm volatile("s_waitcnt vmcnt(0)" ::: "memory");
    __builtin_amdgcn_sched_barrier(0);
  }

  for (int ts = 0; ts < T_LEN; ts++){
    int s_r = ts % 3, s_w = (ts+1) % 3, s_s = (ts+2) % 3;

    if (ts > 0){
      if (kh == 0) asm volatile("s_waitcnt vmcnt(8)" ::: "memory");
      else         asm volatile("s_waitcnt vmcnt(0)" ::: "memory");
      __builtin_amdgcn_sched_barrier(0);
    }

    // ---- input-proj partial over my K-half (A from registers) ----
    f32x4 xR={0.f,0.f,0.f,0.f}, xZ={0.f,0.f,0.f,0.f}, xN={0.f,0.f,0.f,0.f};
    #define ISTEP(qq, kt) { \
      union { u32x4 u; short8 s; } cv; cv.u = qq; \
      int ktg = kh*16 + (kt); \
      int r0 = lj, r1 = 16+lj, r2 = 32+lj; \
      int co = ktg*64 + lg*16; \
      short8 b0 = *(const short8*)(wih_lds + r0*2048 + (co ^ ((r0&7)<<4))); \
      short8 b1 = *(const short8*)(wih_lds + r1*2048 + (co ^ ((r1&7)<<4))); \
      short8 b2 = *(const short8*)(wih_lds + r2*2048 + (co ^ ((r2&7)<<4))); \
      xR = MFMA(cv.s,b0,xR); xZ = MFMA(cv.s,b1,xZ); xN = MFMA(cv.s,b2,xN); \
    }
    ISTEP(ap0,0);  ISTEP(ap1,1);  ISTEP(ap2,2);  ISTEP(ap3,3);
    ISTEP(ap4,4);  ISTEP(ap5,5);  ISTEP(ap6,6);  ISTEP(ap7,7);
    ISTEP(ap8,8);  ISTEP(ap9,9);  ISTEP(ap10,10); ISTEP(ap11,11);
    ISTEP(ap12,12); ISTEP(ap13,13); ISTEP(ap14,14); ISTEP(ap15,15);

    // ---- poll + load my k-half of h(ts): 8 x 16B coherent loads ----
    u32x4 q0,q1,q2,q3,q4,q5,q6,q7;
    {
      const unsigned char* hbase = (const unsigned char*)(hbuf + s_r*64*256)
          + (size_t)(m0+lj)*1024 + (size_t)kh*512 + lg*16;
      unsigned int ok = 0;
      for (int rounds = 0; ok != 0xFFu && rounds < pmax; ++rounds){
        if(!(ok&0x01)) LDQ(q0, hbase, "0");
        if(!(ok&0x02)) LDQ(q1, hbase, "64");
        if(!(ok&0x04)) LDQ(q2, hbase, "128");
        if(!(ok&0x08)) LDQ(q3, hbase, "192");
        if(!(ok&0x10)) LDQ(q4, hbase, "256");
        if(!(ok&0x20)) LDQ(q5, hbase, "320");
        if(!(ok&0x40)) LDQ(q6, hbase, "384");
        if(!(ok&0x80)) LDQ(q7, hbase, "448");
        asm volatile("s_waitcnt vmcnt(0)" ::: "memory");
        __builtin_amdgcn_sched_barrier(0);
        #define CHK2(qq,bit) if(!(ok&bit) && qq[0]!=SENT && qq[1]!=SENT && qq[2]!=SENT && qq[3]!=SENT) ok|=bit
        CHK2(q0,0x01); CHK2(q1,0x02); CHK2(q2,0x04); CHK2(q3,0x08);
        CHK2(q4,0x10); CHK2(q5,0x20); CHK2(q6,0x40); CHK2(q7,0x80);
      }
    }

    // ---- recurrent partial over my k-half ----
    f32x4 aR={0.f,0.f,0.f,0.f}, aZ={0.f,0.f,0.f,0.f}, aN={0.f,0.f,0.f,0.f};
    #define RSTEP1(qq, c) { \
      union { u32x4 u; short8 s; } cv; cv.u = qq; \
      int co = (kh*8 + (c))*64 + lg*16; \
      { int r = lj;    short8 B = *(const short8*)(whh_lds + r*1024 + (co ^ ((r&7)<<4))); aR = MFMA(cv.s, B, aR); } \
      { int r = 16+lj; short8 B = *(const short8*)(whh_lds + r*1024 + (co ^ ((r&7)<<4))); aZ = MFMA(cv.s, B, aZ); } \
      { int r = 32+lj; short8 B = *(const short8*)(whh_lds + r*1024 + (co ^ ((r&7)<<4))); aN = MFMA(cv.s, B, aN); } \
    }
    RSTEP1(q0,0); RSTEP1(q1,1); RSTEP1(q2,2); RSTEP1(q3,3);
    RSTEP1(q4,4); RSTEP1(q5,5); RSTEP1(q6,6); RSTEP1(q7,7);

    // ---- issue A-prefetch for ts+1 ----
    {
      int tn = (ts+1 < T_LEN) ? ts+1 : ts;
      const unsigned char* ab = (const unsigned char*)(l0out + (size_t)(tn*64 + m0 + lj)*1024 + lg*8)
                                + (size_t)kh*1024;
      LDC(ap0,ab,"0");   LDC(ap1,ab,"64");  LDC(ap2,ab,"128"); LDC(ap3,ab,"192");
      LDC(ap4,ab,"256"); LDC(ap5,ab,"320"); LDC(ap6,ab,"384"); LDC(ap7,ab,"448");
      LDC(ap8,ab,"512"); LDC(ap9,ab,"576"); LDC(ap10,ab,"640");LDC(ap11,ab,"704");
      LDC(ap12,ab,"768");LDC(ap13,ab,"832");LDC(ap14,ab,"896");LDC(ap15,ab,"960");
    }

    // ---- SINGLE-PHASE exchange: kh=1 ships all four partials at once ----
    f32x4 tR = xR + aR, tZ = xZ + aZ;
    if (kh == 1){ partA[si] = tR; partB[si] = tZ; partC[si] = xN; partD[si] = aN; }
    __syncthreads();
    f32x4 xNt, aNt;
    if (kh == 0){
      tR += partA[si]; tZ += partB[si];
      xNt = xN + partC[si]; aNt = aN + partD[si];
    }
    __syncthreads();   // protect buffers before next step's writes

    if (kh == 0){
      float hnew[4];
      #pragma unroll
      for (int i=0;i<4;i++){
        float r = sigm(tR[i] + brz);
        float z = sigm(tZ[i] + bzz);
        float nn = tanh_f(xNt[i] + bxn + r*(aNt[i] + bhn));
        hnew[i] = (1.0f - z)*nn + z*hreg[i];
        hreg[i] = hnew[i];
      }
      if (ts < T_LEN-1){
        unsigned int packed[4];
        unsigned long long pk[4];
        #pragma unroll
        for (int i=0;i<4;i++){
          unsigned short mybf = f2bf(hnew[i]);
          unsigned short ot = (unsigned short)__shfl_xor((int)mybf, 1, 64);
          packed[i] = (unsigned int)mybf | ((unsigned int)ot << 16);
        }
        #pragma unroll
        for (int i=0;i<4;i++){
          unsigned int nb = (unsigned int)__shfl_down((int)packed[i], 2, 64);
          pk[i] = (unsigned long long)packed[i] | ((unsigned long long)nb << 32);
        }
        if ((l & 3) == 0){
          unsigned long long* hs = (unsigned long long*)(hbuf + s_s*64*256);
          unsigned long long* hw = (unsigned long long*)(hbuf + s_w*64*256);
          #pragma unroll
          for (int i=0;i<4;i++){
            int b = m0 + lg*4 + i;
            size_t qi = ((size_t)b*256 + (jg>>1)) >> 1;
            STQ(hs + qi, 0xFFFFFFFFFFFFFFFFull);
            STQ(hw + qi, pk[i]);
          }
        }
      } else {
        #pragma unroll
        for (int i=0;i<4;i++)
          l1cat[(size_t)(m0 + lg*4 + i)*1024 + jg] = hnew[i];
      }
    }
  }
}

// ---------------- final FC ----------------
__global__ void k_fc(const float* __restrict__ l1cat, const float* __restrict__ fcw,
                     const float* __restrict__ fcb, float* __restrict__ out){
  int idx = blockIdx.x*256 + threadIdx.x;
  if (idx >= 64*12) return;
  int b = idx / 12, o = idx % 12;
  float s = fcb[o];
  for (int k=0;k<1024;k++) s += l1cat[b*1024+k]*fcw[o*1024+k];
  out[idx] = s;
}

extern "C" void kernel_launch(void* const* d_in, const int* in_sizes, int n_in,
                              void* d_out, int out_size, void* d_ws, size_t ws_size,
                              hipStream_t stream){
  const float* x     = (const float*)d_in[0];
  const float* wih0f = (const float*)d_in[1];
  const float* whh0f = (const float*)d_in[2];
  const float* bih0f = (const float*)d_in[3];
  const float* bhh0f = (const float*)d_in[4];
  const float* wih0b = (const float*)d_in[5];
  const float* whh0b = (const float*)d_in[6];
  const float* bih0b = (const float*)d_in[7];
  const float* bhh0b = (const float*)d_in[8];
  const float* wih1f = (const float*)d_in[9];
  const float* whh1f = (const float*)d_in[10];
  const float* bih1f = (const float*)d_in[11];
  const float* bhh1f = (const float*)d_in[12];
  const float* wih1b = (const float*)d_in[13];
  const float* bih1b = (const float*)d_in[15];
  const float* bhh1b = (const float*)d_in[16];
  const float* fcw   = (const float*)d_in[17];
  const float* fcb   = (const float*)d_in[18];

  const size_t SLOT = (size_t)64*256*4;   // 64 KB per ring slot

  char* ws = (char*)d_ws;
  size_t off = 0;
  auto alloc = [&](size_t bytes)->void*{ void* p = ws + off; off = (off + bytes + 255) & ~(size_t)255; return p; };
  unsigned short* xT    = (unsigned short*)alloc((size_t)64000*96*2);
  unsigned short* whh0c = (unsigned short*)alloc((size_t)2*1536*512*2);
  unsigned short* wih0c = (unsigned short*)alloc((size_t)2*1536*96*2);
  unsigned short* wih1c = (unsigned short*)alloc((size_t)2*1536*1024*2);
  unsigned short* whh1c = (unsigned short*)alloc((size_t)1536*512*2);
  unsigned short* l0out = (unsigned short*)alloc((size_t)64000*1024*2);
  unsigned int*   hbB   = (unsigned int*)alloc((size_t)2*3*SLOT);   // [2][3][64][256]
  unsigned int*   hbD   = (unsigned int*)alloc((size_t)3*SLOT);     // [3][64][256]
  float*          l1cat = (float*)alloc((size_t)64*1024*4);

  if (off > ws_size){
    k_sentinel<<<(out_size+255)/256,256,0,stream>>>((float*)d_out, out_size);
    return;
  }

  // fused conversions + ring init (2 launches)
  k_convall<<<22656,256,0,stream>>>(whh0f, whh0b, wih0f, wih0b, wih1f, wih1b, whh1f,
                                    whh0c, wih0c, wih1c, whh1c);
  k_ringinit<<<576,256,0,stream>>>(hbB, hbD);
  k_xpose<<<1024,64,0,stream>>>(x, xT);

  k_gru0<<<32,512,0,stream>>>(xT, whh0c, wih0c, bih0f,bhh0f,bih0b,bhh0b, l0out, hbB, 30000);
  k_gru1<<<64,512,0,stream>>>(l0out, wih1c, whh1c, bih1f,bhh1f,bih1b,bhh1b, l1cat, hbD, 30000);
  k_fc<<<3,256,0,stream>>>(l1cat, fcw, fcb, (float*)d_out);
}